// Round 5
// baseline (368.018 us; speedup 1.0000x reference)
//
#include <hip/hip_runtime.h>
#include <hip/hip_bf16.h>

#define N_NODES 50000
#define N_EDGES 800000
#define IN_CH 256
#define HEADS 8
#define OUT_CH 32
#define HC 256            // HEADS*OUT_CH
#define E_TOT (N_EDGES + N_NODES)
#define NEG_SLOPE 0.2f

typedef short s16x8 __attribute__((ext_vector_type(8)));
typedef float f32x4 __attribute__((ext_vector_type(4)));

// ---- bf16 helpers via raw bits (RNE) ----
__device__ __forceinline__ unsigned short f2bf(float f) {
    unsigned int u = __float_as_uint(f);
    unsigned int r = (u + 0x7FFFu + ((u >> 16) & 1u)) >> 16;
    return (unsigned short)r;
}
__device__ __forceinline__ float bf2f(unsigned short b) {
    return __uint_as_float(((unsigned int)b) << 16);
}

// Swizzled byte offset in a [rows][32] bf16 LDS tile (row stride 64 B).
// XOR byte-bit4 with row&7: ds_read_b128 column reads conflict-free (G4).
__device__ __forceinline__ int tbyte(int r, int k2) { return (r * 64 + k2) ^ ((r & 7) << 4); }

// ---------------- W fp32 -> bf16 pre-convert (once, 64K elems) ----------------
__global__ void wconv_kernel(const float* __restrict__ W, unsigned short* __restrict__ Wb) {
    int i = (blockIdx.x * 256 + threadIdx.x) * 4;
    float4 v = *(const float4*)&W[i];
    ushort4 o; o.x = f2bf(v.x); o.y = f2bf(v.y); o.z = f2bf(v.z); o.w = f2bf(v.w);
    *(ushort4*)&Wb[i] = o;
}

// ---------------- GEMM: Wh(bf16) = x @ W^T via MFMA, fused el/er epilogue ----
// M=50000, N=256, K=256. Block: 128 rows x 256 cols, 512 thr = 8 waves.
// Wave (wr=wv&3, wc=wv>>2): rows wr*32..+31 (2 m-tiles), cols wc*128..+127 (8 n-tiles).
__global__ __launch_bounds__(512) void gemm_kernel(const float* __restrict__ x,
                                                   const unsigned short* __restrict__ Wb,
                                                   const float* __restrict__ a_left,
                                                   const float* __restrict__ a_right,
                                                   unsigned short* __restrict__ Wh,
                                                   float* __restrict__ el,
                                                   float* __restrict__ er) {
    __shared__ unsigned short As[128 * 32];   // 8 KB
    __shared__ unsigned short Bs[256 * 32];   // 16 KB
    char* Asb = (char*)As;
    char* Bsb = (char*)Bs;
    const int m0 = blockIdx.x * 128;
    const int t  = threadIdx.x;
    const int l  = t & 63;
    const int wv = t >> 6;
    const int wr = wv & 3;        // 32-row group
    const int wc = wv >> 2;       // 0..1: 128-col half
    const int c16  = l & 15;
    const int rgrp = l >> 4;      // 0..3

    f32x4 acc[2][8];
#pragma unroll
    for (int i = 0; i < 2; ++i)
#pragma unroll
        for (int j = 0; j < 8; ++j) acc[i][j] = (f32x4){0.f, 0.f, 0.f, 0.f};

    for (int k0 = 0; k0 < IN_CH; k0 += 32) {
        {   // stage A: 128 rows x 32 k from fp32 x, 8 elems/thread
            int r = t >> 2, kq = (t & 3) << 3;
            float4 v0 = make_float4(0.f, 0.f, 0.f, 0.f), v1 = v0;
            if (m0 + r < N_NODES) {
                const float* xp = &x[(size_t)(m0 + r) * IN_CH + k0 + kq];
                v0 = *(const float4*)(xp + 0);
                v1 = *(const float4*)(xp + 4);
            }
            ushort4 o0, o1;
            o0.x = f2bf(v0.x); o0.y = f2bf(v0.y); o0.z = f2bf(v0.z); o0.w = f2bf(v0.w);
            o1.x = f2bf(v1.x); o1.y = f2bf(v1.y); o1.z = f2bf(v1.z); o1.w = f2bf(v1.w);
            int b0 = kq * 2;
            *(ushort4*)(Asb + tbyte(r, b0 + 0)) = o0;
            *(ushort4*)(Asb + tbyte(r, b0 + 8)) = o1;
        }
        {   // stage B: 256 rows x 32 k from bf16 Wb, 16 elems/thread (pure copy)
            int r = t >> 1, kq = (t & 1) << 4;
            const unsigned short* wp = &Wb[(size_t)r * IN_CH + k0 + kq];
            ushort4 w0 = *(const ushort4*)(wp + 0);
            ushort4 w1 = *(const ushort4*)(wp + 4);
            ushort4 w2 = *(const ushort4*)(wp + 8);
            ushort4 w3 = *(const ushort4*)(wp + 12);
            int b0 = kq * 2;
            *(ushort4*)(Bsb + tbyte(r, b0 + 0))  = w0;
            *(ushort4*)(Bsb + tbyte(r, b0 + 8))  = w1;
            *(ushort4*)(Bsb + tbyte(r, b0 + 16)) = w2;
            *(ushort4*)(Bsb + tbyte(r, b0 + 24)) = w3;
        }
        __syncthreads();
        s16x8 af0 = *(const s16x8*)(Asb + tbyte(wr * 32 + c16,      rgrp * 16));
        s16x8 af1 = *(const s16x8*)(Asb + tbyte(wr * 32 + 16 + c16, rgrp * 16));
#pragma unroll
        for (int nt = 0; nt < 8; ++nt) {
            s16x8 bf = *(const s16x8*)(Bsb + tbyte(wc * 128 + nt * 16 + c16, rgrp * 16));
            acc[0][nt] = __builtin_amdgcn_mfma_f32_16x16x32_bf16(af0, bf, acc[0][nt], 0, 0, 0);
            acc[1][nt] = __builtin_amdgcn_mfma_f32_16x16x32_bf16(af1, bf, acc[1][nt], 0, 0, 0);
        }
        __syncthreads();
    }

    // Epilogue. C/D layout (m89): col = lane&15, row = (lane>>4)*4 + reg.
#pragma unroll
    for (int mt = 0; mt < 2; ++mt) {
#pragma unroll
        for (int hp = 0; hp < 4; ++hp) {
            int hg  = wc * 4 + hp;
            int nt0 = hp * 2;
            float al0 = a_left [hg * OUT_CH + c16];
            float al1 = a_left [hg * OUT_CH + 16 + c16];
            float ar0 = a_right[hg * OUT_CH + c16];
            float ar1 = a_right[hg * OUT_CH + 16 + c16];
#pragma unroll
            for (int rg = 0; rg < 4; ++rg) {
                float pl = acc[mt][nt0][rg] * al0 + acc[mt][nt0 + 1][rg] * al1;
                float pr = acc[mt][nt0][rg] * ar0 + acc[mt][nt0 + 1][rg] * ar1;
#pragma unroll
                for (int m = 1; m < 16; m <<= 1) {
                    pl += __shfl_xor(pl, m, 16);
                    pr += __shfl_xor(pr, m, 16);
                }
                int row = m0 + wr * 32 + mt * 16 + rgrp * 4 + rg;
                if (c16 == 0 && row < N_NODES) {
                    el[row * HEADS + hg] = pl;
                    er[row * HEADS + hg] = pr;
                }
            }
        }
#pragma unroll
        for (int nt = 0; nt < 8; ++nt) {
#pragma unroll
            for (int rg = 0; rg < 4; ++rg) {
                int row = m0 + wr * 32 + mt * 16 + rgrp * 4 + rg;
                if (row < N_NODES)
                    Wh[(size_t)row * HC + wc * 128 + nt * 16 + c16] = f2bf(acc[mt][nt][rg]);
            }
        }
    }
}

// ---------------- CSR build ----------------
__global__ void zero_kernel(int* __restrict__ p, int n) {
    int i = blockIdx.x * blockDim.x + threadIdx.x;
    if (i < n) p[i] = 0;
}

__global__ void hist_kernel(const int* __restrict__ src, const int* __restrict__ dst,
                            int* __restrict__ count) {
    int e = blockIdx.x * blockDim.x + threadIdx.x;
    if (e >= E_TOT) return;
    int s, d;
    if (e < N_EDGES) { s = src[e]; d = dst[e]; } else { s = d = e - N_EDGES; }
    if ((unsigned)s >= N_NODES || (unsigned)d >= N_NODES) return;  // fault-proofing
    atomicAdd(&count[d], 1);
}

__global__ __launch_bounds__(1024) void scan_kernel(const int* __restrict__ count,
                                                    int* __restrict__ offset,
                                                    int* __restrict__ cursor) {
    __shared__ int wtot[16];
    __shared__ int wbase[16];
    __shared__ int running_s;
    int t = threadIdx.x, lane = t & 63, wid = t >> 6;
    if (t == 0) running_s = 0;
    __syncthreads();
    for (int base = 0; base < N_NODES; base += 1024) {
        int idx = base + t;
        int v = (idx < N_NODES) ? count[idx] : 0;
        int s = v;
#pragma unroll
        for (int off = 1; off < 64; off <<= 1) {
            int u = __shfl_up(s, off, 64);
            if (lane >= off) s += u;
        }
        if (lane == 63) wtot[wid] = s;
        __syncthreads();
        if (t == 0) {
            int b = running_s;
            for (int w = 0; w < 16; ++w) { wbase[w] = b; b += wtot[w]; }
            running_s = b;
        }
        __syncthreads();
        int excl = s - v + wbase[wid];
        if (idx < N_NODES) { offset[idx] = excl; cursor[idx] = excl; }
        __syncthreads();
    }
    if (t == 0) offset[N_NODES] = running_s;
}

__global__ void scatter_kernel(const int* __restrict__ src, const int* __restrict__ dst,
                               int* __restrict__ cursor, int* __restrict__ srcs) {
    int e = blockIdx.x * blockDim.x + threadIdx.x;
    if (e >= E_TOT) return;
    int s, d;
    if (e < N_EDGES) { s = src[e]; d = dst[e]; } else { s = d = e - N_EDGES; }
    if ((unsigned)s >= N_NODES || (unsigned)d >= N_NODES) return;
    int pos = atomicAdd(&cursor[d], 1);
    srcs[pos] = s;
}

// ---------------- softmax + aggregation: one block per dst node ----------------
// Chunked: per 64-edge chunk, each head's 32 threads compute each exp ONCE
// (denominator accumulated in-register during fill), stash e[64][8] + s[64] in
// LDS; consume loop is {LDS broadcast, Wh gather, fma}. Softmax shift-invariance
// makes the max-pass unnecessary (scores O(+-10), fp32 exp safe; self-loop =>
// non-empty segment).
__global__ __launch_bounds__(256) void agg_kernel(const unsigned short* __restrict__ Wh,
                                                  const float* __restrict__ el,
                                                  const float* __restrict__ er,
                                                  const int* __restrict__ offset,
                                                  const int* __restrict__ srcs,
                                                  float* __restrict__ out) {
    __shared__ float e_sh[64][HEADS];
    __shared__ int   s_sh[64];
    int n = blockIdx.x;
    int t = threadIdx.x;
    int h = t >> 5;
    int l32 = t & 31;
    float ern = er[n * HEADS + h];
    int start = offset[n], end = offset[n + 1];
    float acc = 0.f, denp = 0.f;

    for (int c0 = start; c0 < end; c0 += 64) {
        int m = min(64, end - c0);
        // fill: head h's 32 threads cover edges l32, l32+32 of the chunk
#pragma unroll 2
        for (int jj = l32; jj < m; jj += 32) {
            int s = srcs[c0 + jj];
            if (h == 0) s_sh[jj] = s;
            float sc = el[s * HEADS + h] + ern;
            sc = fmaxf(sc, NEG_SLOPE * sc);       // leaky-relu
            float e = __expf(sc);
            e_sh[jj][h] = e;
            denp += e;
        }
        __syncthreads();
#pragma unroll 4
        for (int jj = 0; jj < m; ++jj) {
            int s   = s_sh[jj];
            float e = e_sh[jj][h];
            acc = fmaf(e, bf2f(Wh[(size_t)s * HC + t]), acc);
        }
        __syncthreads();
    }
    // reduce denominator across the head's 32 lanes (xor<32 stays in-half)
#pragma unroll
    for (int m = 16; m >= 1; m >>= 1) denp += __shfl_xor(denp, m);
    out[(size_t)n * HC + t] = acc / (denp + 1e-16f);
}

// Diagnostic: ws too small -> absmax ~1e6 identifies the cause.
__global__ void sentinel_kernel(float* __restrict__ out, int n) {
    int i = blockIdx.x * blockDim.x + threadIdx.x;
    if (i < n) out[i] = 1.0e6f;
}

extern "C" void kernel_launch(void* const* d_in, const int* in_sizes, int n_in,
                              void* d_out, int out_size, void* d_ws, size_t ws_size,
                              hipStream_t stream) {
    const float* x       = (const float*)d_in[0];
    const int*   ei      = (const int*)d_in[1];    // [2, E] int32
    const float* W       = (const float*)d_in[2];
    const float* a_left  = (const float*)d_in[3];
    const float* a_right = (const float*)d_in[4];
    float* out = (float*)d_out;

    const int* src = ei;
    const int* dst = ei + N_EDGES;

    char* ws = (char*)d_ws;
    size_t off = 0;
    auto alloc = [&](size_t bytes) -> void* {
        void* p = ws + off;
        off += (bytes + 255) & ~(size_t)255;
        return p;
    };
    unsigned short* Wh = (unsigned short*)alloc((size_t)N_NODES * HC * sizeof(unsigned short)); // 25.6 MB
    float* el     = (float*)alloc((size_t)N_NODES * HEADS * sizeof(float));
    float* er     = (float*)alloc((size_t)N_NODES * HEADS * sizeof(float));
    int*   count  = (int*)alloc((size_t)N_NODES * sizeof(int));
    int*   offset = (int*)alloc((size_t)(N_NODES + 1) * sizeof(int));
    int*   cursor = (int*)alloc((size_t)N_NODES * sizeof(int));
    int*   srcs   = (int*)alloc((size_t)E_TOT * sizeof(int));
    unsigned short* Wb = (unsigned short*)alloc((size_t)HC * IN_CH * sizeof(unsigned short)); // 128 KB
    // total ~32.9 MB

    if (off > ws_size) {
        sentinel_kernel<<<(out_size + 255) / 256, 256, 0, stream>>>(out, out_size);
        return;
    }

    wconv_kernel<<<(HC * IN_CH) / 1024, 256, 0, stream>>>(W, Wb);
    gemm_kernel<<<(N_NODES + 127) / 128, 512, 0, stream>>>(x, Wb, a_left, a_right, Wh, el, er);

    zero_kernel<<<(N_NODES + 255) / 256, 256, 0, stream>>>(count, N_NODES);
    int eblocks = (E_TOT + 255) / 256;
    hist_kernel<<<eblocks, 256, 0, stream>>>(src, dst, count);
    scan_kernel<<<1, 1024, 0, stream>>>(count, offset, cursor);
    scatter_kernel<<<eblocks, 256, 0, stream>>>(src, dst, cursor, srcs);

    agg_kernel<<<N_NODES, 256, 0, stream>>>(Wh, el, er, offset, srcs, out);
}

// Round 6
// 326.371 us; speedup vs baseline: 1.1276x; 1.1276x over previous
//
#include <hip/hip_runtime.h>
#include <hip/hip_bf16.h>

#define N_NODES 50000
#define N_EDGES 800000
#define IN_CH 256
#define HEADS 8
#define OUT_CH 32
#define HC 256            // HEADS*OUT_CH
#define E_TOT (N_EDGES + N_NODES)
#define NEG_SLOPE 0.2f
#define NB 196            // ceil(N_NODES/256)

typedef short s16x8 __attribute__((ext_vector_type(8)));
typedef float f32x4 __attribute__((ext_vector_type(4)));

// ---- bf16 helpers via raw bits (RNE) ----
__device__ __forceinline__ unsigned short f2bf(float f) {
    unsigned int u = __float_as_uint(f);
    unsigned int r = (u + 0x7FFFu + ((u >> 16) & 1u)) >> 16;
    return (unsigned short)r;
}
__device__ __forceinline__ float bf2f(unsigned short b) {
    return __uint_as_float(((unsigned int)b) << 16);
}

// Swizzled byte offset in a [rows][32] bf16 LDS tile (row stride 64 B).
__device__ __forceinline__ int tbyte(int r, int k2) { return (r * 64 + k2) ^ ((r & 7) << 4); }

// ---------------- W fp32 -> bf16 pre-convert (once, 64K elems) ----------------
__global__ void wconv_kernel(const float* __restrict__ W, unsigned short* __restrict__ Wb) {
    int i = (blockIdx.x * 256 + threadIdx.x) * 4;
    float4 v = *(const float4*)&W[i];
    ushort4 o; o.x = f2bf(v.x); o.y = f2bf(v.y); o.z = f2bf(v.z); o.w = f2bf(v.w);
    *(ushort4*)&Wb[i] = o;
}

// ---------------- GEMM: Wh(bf16) = x @ W^T via MFMA, fused el/er epilogue ----
__global__ __launch_bounds__(512) void gemm_kernel(const float* __restrict__ x,
                                                   const unsigned short* __restrict__ Wb,
                                                   const float* __restrict__ a_left,
                                                   const float* __restrict__ a_right,
                                                   unsigned short* __restrict__ Wh,
                                                   float* __restrict__ el,
                                                   float* __restrict__ er) {
    __shared__ unsigned short As[128 * 32];   // 8 KB
    __shared__ unsigned short Bs[256 * 32];   // 16 KB
    char* Asb = (char*)As;
    char* Bsb = (char*)Bs;
    const int m0 = blockIdx.x * 128;
    const int t  = threadIdx.x;
    const int l  = t & 63;
    const int wv = t >> 6;
    const int wr = wv & 3;        // 32-row group
    const int wc = wv >> 2;       // 0..1: 128-col half
    const int c16  = l & 15;
    const int rgrp = l >> 4;      // 0..3

    f32x4 acc[2][8];
#pragma unroll
    for (int i = 0; i < 2; ++i)
#pragma unroll
        for (int j = 0; j < 8; ++j) acc[i][j] = (f32x4){0.f, 0.f, 0.f, 0.f};

    for (int k0 = 0; k0 < IN_CH; k0 += 32) {
        {   // stage A: 128 rows x 32 k from fp32 x, 8 elems/thread
            int r = t >> 2, kq = (t & 3) << 3;
            float4 v0 = make_float4(0.f, 0.f, 0.f, 0.f), v1 = v0;
            if (m0 + r < N_NODES) {
                const float* xp = &x[(size_t)(m0 + r) * IN_CH + k0 + kq];
                v0 = *(const float4*)(xp + 0);
                v1 = *(const float4*)(xp + 4);
            }
            ushort4 o0, o1;
            o0.x = f2bf(v0.x); o0.y = f2bf(v0.y); o0.z = f2bf(v0.z); o0.w = f2bf(v0.w);
            o1.x = f2bf(v1.x); o1.y = f2bf(v1.y); o1.z = f2bf(v1.z); o1.w = f2bf(v1.w);
            int b0 = kq * 2;
            *(ushort4*)(Asb + tbyte(r, b0 + 0)) = o0;
            *(ushort4*)(Asb + tbyte(r, b0 + 8)) = o1;
        }
        {   // stage B: 256 rows x 32 k from bf16 Wb, 16 elems/thread (pure copy)
            int r = t >> 1, kq = (t & 1) << 4;
            const unsigned short* wp = &Wb[(size_t)r * IN_CH + k0 + kq];
            ushort4 w0 = *(const ushort4*)(wp + 0);
            ushort4 w1 = *(const ushort4*)(wp + 4);
            ushort4 w2 = *(const ushort4*)(wp + 8);
            ushort4 w3 = *(const ushort4*)(wp + 12);
            int b0 = kq * 2;
            *(ushort4*)(Bsb + tbyte(r, b0 + 0))  = w0;
            *(ushort4*)(Bsb + tbyte(r, b0 + 8))  = w1;
            *(ushort4*)(Bsb + tbyte(r, b0 + 16)) = w2;
            *(ushort4*)(Bsb + tbyte(r, b0 + 24)) = w3;
        }
        __syncthreads();
        s16x8 af0 = *(const s16x8*)(Asb + tbyte(wr * 32 + c16,      rgrp * 16));
        s16x8 af1 = *(const s16x8*)(Asb + tbyte(wr * 32 + 16 + c16, rgrp * 16));
#pragma unroll
        for (int nt = 0; nt < 8; ++nt) {
            s16x8 bf = *(const s16x8*)(Bsb + tbyte(wc * 128 + nt * 16 + c16, rgrp * 16));
            acc[0][nt] = __builtin_amdgcn_mfma_f32_16x16x32_bf16(af0, bf, acc[0][nt], 0, 0, 0);
            acc[1][nt] = __builtin_amdgcn_mfma_f32_16x16x32_bf16(af1, bf, acc[1][nt], 0, 0, 0);
        }
        __syncthreads();
    }

    // Epilogue. C/D layout (m89): col = lane&15, row = (lane>>4)*4 + reg.
#pragma unroll
    for (int mt = 0; mt < 2; ++mt) {
#pragma unroll
        for (int hp = 0; hp < 4; ++hp) {
            int hg  = wc * 4 + hp;
            int nt0 = hp * 2;
            float al0 = a_left [hg * OUT_CH + c16];
            float al1 = a_left [hg * OUT_CH + 16 + c16];
            float ar0 = a_right[hg * OUT_CH + c16];
            float ar1 = a_right[hg * OUT_CH + 16 + c16];
#pragma unroll
            for (int rg = 0; rg < 4; ++rg) {
                float pl = acc[mt][nt0][rg] * al0 + acc[mt][nt0 + 1][rg] * al1;
                float pr = acc[mt][nt0][rg] * ar0 + acc[mt][nt0 + 1][rg] * ar1;
#pragma unroll
                for (int m = 1; m < 16; m <<= 1) {
                    pl += __shfl_xor(pl, m, 16);
                    pr += __shfl_xor(pr, m, 16);
                }
                int row = m0 + wr * 32 + mt * 16 + rgrp * 4 + rg;
                if (c16 == 0 && row < N_NODES) {
                    el[row * HEADS + hg] = pl;
                    er[row * HEADS + hg] = pr;
                }
            }
        }
#pragma unroll
        for (int nt = 0; nt < 8; ++nt) {
#pragma unroll
            for (int rg = 0; rg < 4; ++rg) {
                int row = m0 + wr * 32 + mt * 16 + rgrp * 4 + rg;
                if (row < N_NODES)
                    Wh[(size_t)row * HC + wc * 128 + nt * 16 + c16] = f2bf(acc[mt][nt][rg]);
            }
        }
    }
}

// ---------------- CSR build ----------------
__global__ void zero_kernel(int* __restrict__ p, int n) {
    int i = blockIdx.x * blockDim.x + threadIdx.x;
    if (i < n) p[i] = 0;
}

__global__ void hist_kernel(const int* __restrict__ src, const int* __restrict__ dst,
                            int* __restrict__ count) {
    int e = blockIdx.x * blockDim.x + threadIdx.x;
    if (e >= E_TOT) return;
    int s, d;
    if (e < N_EDGES) { s = src[e]; d = dst[e]; } else { s = d = e - N_EDGES; }
    if ((unsigned)s >= N_NODES || (unsigned)d >= N_NODES) return;  // fault-proofing
    atomicAdd(&count[d], 1);
}

// Multi-block scan: per-block local exclusive scan + block totals.
__global__ __launch_bounds__(256) void scan_part(const int* __restrict__ count,
                                                 int* __restrict__ loc,
                                                 int* __restrict__ btot) {
    __shared__ int wt[4], wb[4];
    int t = threadIdx.x, lane = t & 63, wid = t >> 6;
    int idx = blockIdx.x * 256 + t;
    int v = (idx < N_NODES) ? count[idx] : 0;
    int s = v;
#pragma unroll
    for (int off = 1; off < 64; off <<= 1) {
        int u = __shfl_up(s, off, 64);
        if (lane >= off) s += u;
    }
    if (lane == 63) wt[wid] = s;
    __syncthreads();
    if (t == 0) {
        int a = 0;
        for (int w = 0; w < 4; ++w) { wb[w] = a; a += wt[w]; }
        btot[blockIdx.x] = a;
    }
    __syncthreads();
    if (idx < N_NODES) loc[idx] = s - v + wb[wid];
}

// Exclusive scan of the NB block totals (single block).
__global__ __launch_bounds__(256) void scan_tops(const int* __restrict__ btot,
                                                 int* __restrict__ bbase) {
    __shared__ int wt[4], wb[4];
    int t = threadIdx.x, lane = t & 63, wid = t >> 6;
    int v = (t < NB) ? btot[t] : 0;
    int s = v;
#pragma unroll
    for (int off = 1; off < 64; off <<= 1) {
        int u = __shfl_up(s, off, 64);
        if (lane >= off) s += u;
    }
    if (lane == 63) wt[wid] = s;
    __syncthreads();
    if (t == 0) {
        int a = 0;
        for (int w = 0; w < 4; ++w) { wb[w] = a; a += wt[w]; }
    }
    __syncthreads();
    if (t < NB) bbase[t] = s - v + wb[wid];
}

__global__ __launch_bounds__(256) void scan_apply(int* __restrict__ offset,
                                                  const int* __restrict__ bbase,
                                                  int* __restrict__ cursor) {
    int idx = blockIdx.x * 256 + threadIdx.x;
    if (idx == 0) offset[N_NODES] = E_TOT;   // all indices in-range by construction
    if (idx < N_NODES) {
        int o = offset[idx] + bbase[blockIdx.x];
        offset[idx] = o;
        cursor[idx] = o;
    }
}

__global__ void scatter_kernel(const int* __restrict__ src, const int* __restrict__ dst,
                               int* __restrict__ cursor, int* __restrict__ srcs) {
    int e = blockIdx.x * blockDim.x + threadIdx.x;
    if (e >= E_TOT) return;
    int s, d;
    if (e < N_EDGES) { s = src[e]; d = dst[e]; } else { s = d = e - N_EDGES; }
    if ((unsigned)s >= N_NODES || (unsigned)d >= N_NODES) return;
    int pos = atomicAdd(&cursor[d], 1);
    srcs[pos] = s;
}

// ---------------- softmax + aggregation: one node per 64-lane WAVE ----------
// 2 independent nodes per 128-thr block, no LDS, no barriers (wave-synchronous).
// Lane l: head h=l>>3, sub i=l&7, owns channels h*32+i*4..+3 (ushort4 gather,
// 8 B/lane; wave covers the full 512 B Wh row). Per 64-edge chunk: fill computes
// each exp ONCE per (edge,head) into e[8] (static idx); consume redistributes
// via shfl/bpermute. Softmax shift-invariance: no max pass (scores O(+-10),
// self-loop => non-empty segment).
__global__ __launch_bounds__(128) void agg_kernel(const unsigned short* __restrict__ Wh,
                                                  const float* __restrict__ el,
                                                  const float* __restrict__ er,
                                                  const int* __restrict__ offset,
                                                  const int* __restrict__ srcs,
                                                  float* __restrict__ out) {
    int n = blockIdx.x * 2 + (threadIdx.x >> 6);
    if (n >= N_NODES) return;
    int l = threadIdx.x & 63;
    int h = l >> 3;
    int i = l & 7;
    float ern = er[n * HEADS + h];
    int start = offset[n], end = offset[n + 1];
    f32x4 acc = {0.f, 0.f, 0.f, 0.f};
    float den = 0.f;

    for (int c0 = start; c0 < end; c0 += 64) {
        int m = end - c0; if (m > 64) m = 64;
        int sv = (l < m) ? srcs[c0 + l] : 0;   // one coalesced index load per lane

        // fill: lane (h,i) computes e for edges jj = i+8k, head h
        float e[8];
#pragma unroll
        for (int k = 0; k < 8; ++k) {
            if (8 * k >= m) break;             // uniform early-exit
            int jj = i + 8 * k;
            int s = __shfl(sv, jj, 64);        // bpermute
            float sc = el[s * HEADS + h] + ern;
            sc = fmaxf(sc, NEG_SLOPE * sc);    // leaky-relu
            float ev = (jj < m) ? __expf(sc) : 0.f;
            e[k] = ev;
            den += ev;
        }

        // consume: edge jj -> e(jj,h) lives in lane h*8+(jj&7), reg jj>>3
#pragma unroll
        for (int k = 0; k < 8; ++k) {
            if (8 * k >= m) break;
#pragma unroll
            for (int q = 0; q < 8; ++q) {
                int jj = k * 8 + q;
                if (jj >= m) break;            // uniform
                float ev = __shfl(e[k], h * 8 + q, 64);  // bpermute
                int   s  = __shfl(sv, jj, 64);           // broadcast
                ushort4 w = *(const ushort4*)&Wh[(size_t)s * HC + h * 32 + i * 4];
                acc.x = fmaf(ev, bf2f(w.x), acc.x);
                acc.y = fmaf(ev, bf2f(w.y), acc.y);
                acc.z = fmaf(ev, bf2f(w.z), acc.z);
                acc.w = fmaf(ev, bf2f(w.w), acc.w);
            }
        }
    }
    // reduce den across the head's 8 lanes (xor<8 stays in-group)
#pragma unroll
    for (int msk = 4; msk >= 1; msk >>= 1) den += __shfl_xor(den, msk, 64);
    float inv = 1.0f / (den + 1e-16f);
    float4 o = make_float4(acc.x * inv, acc.y * inv, acc.z * inv, acc.w * inv);
    *(float4*)&out[(size_t)n * HC + h * 32 + i * 4] = o;
}

// Diagnostic: ws too small -> absmax ~1e6 identifies the cause.
__global__ void sentinel_kernel(float* __restrict__ out, int n) {
    int i = blockIdx.x * blockDim.x + threadIdx.x;
    if (i < n) out[i] = 1.0e6f;
}

extern "C" void kernel_launch(void* const* d_in, const int* in_sizes, int n_in,
                              void* d_out, int out_size, void* d_ws, size_t ws_size,
                              hipStream_t stream) {
    const float* x       = (const float*)d_in[0];
    const int*   ei      = (const int*)d_in[1];    // [2, E] int32
    const float* W       = (const float*)d_in[2];
    const float* a_left  = (const float*)d_in[3];
    const float* a_right = (const float*)d_in[4];
    float* out = (float*)d_out;

    const int* src = ei;
    const int* dst = ei + N_EDGES;

    char* ws = (char*)d_ws;
    size_t off = 0;
    auto alloc = [&](size_t bytes) -> void* {
        void* p = ws + off;
        off += (bytes + 255) & ~(size_t)255;
        return p;
    };
    unsigned short* Wh = (unsigned short*)alloc((size_t)N_NODES * HC * sizeof(unsigned short)); // 25.6 MB
    float* el     = (float*)alloc((size_t)N_NODES * HEADS * sizeof(float));
    float* er     = (float*)alloc((size_t)N_NODES * HEADS * sizeof(float));
    int*   count  = (int*)alloc((size_t)N_NODES * sizeof(int));
    int*   offset = (int*)alloc((size_t)(N_NODES + 1) * sizeof(int));
    int*   cursor = (int*)alloc((size_t)N_NODES * sizeof(int));
    int*   srcs   = (int*)alloc((size_t)E_TOT * sizeof(int));
    unsigned short* Wb = (unsigned short*)alloc((size_t)HC * IN_CH * sizeof(unsigned short)); // 128 KB
    int*   btot   = (int*)alloc((size_t)NB * sizeof(int));
    int*   bbase  = (int*)alloc((size_t)NB * sizeof(int));
    // total ~32.9 MB

    if (off > ws_size) {
        sentinel_kernel<<<(out_size + 255) / 256, 256, 0, stream>>>(out, out_size);
        return;
    }

    wconv_kernel<<<(HC * IN_CH) / 1024, 256, 0, stream>>>(W, Wb);
    gemm_kernel<<<(N_NODES + 127) / 128, 512, 0, stream>>>(x, Wb, a_left, a_right, Wh, el, er);

    zero_kernel<<<(N_NODES + 255) / 256, 256, 0, stream>>>(count, N_NODES);
    int eblocks = (E_TOT + 255) / 256;
    hist_kernel<<<eblocks, 256, 0, stream>>>(src, dst, count);
    scan_part<<<NB, 256, 0, stream>>>(count, offset, btot);
    scan_tops<<<1, 256, 0, stream>>>(btot, bbase);
    scan_apply<<<NB, 256, 0, stream>>>(offset, bbase, cursor);
    scatter_kernel<<<eblocks, 256, 0, stream>>>(src, dst, cursor, srcs);

    agg_kernel<<<(N_NODES + 1) / 2, 128, 0, stream>>>(Wh, el, er, offset, srcs, out);
}